// Round 8
// baseline (230.106 us; speedup 1.0000x reference)
//
#include <hip/hip_runtime.h>
#include <hip/hip_bf16.h>

#define EMBED 768
#define HID 768
#define DTOT 1536
#define NASP 32
#define BATCHN 256
#define CH 16        // samples per chunk
#define MAXCHUNK 48  // sum ceil(n_a/16) <= 48 (overflow chunks handled by +32 loop)
#define NTILE 6      // 768 / 128 column tiles
#define DSPLIT 8     // 1536 / 192 row splits
#define DROWS (DTOT / DSPLIT)   // 192 rows per block

// grid = 32*NTILE*DSPLIT = 1536 blocks = exactly 6/CU, all co-resident at
// launch_bounds(256,6). Chunk ids >= 32 (rare: aspect with >16 samples) are
// processed by the block owning (chunk-32) via the c += 32 loop.

__global__ __launch_bounds__(256, 6) void gemv1_kernel(
    const float* __restrict__ vX, const float* __restrict__ vH,
    const float* __restrict__ W1, const int* __restrict__ aspect_ids,
    float* __restrict__ part)
{
    __shared__ int wcnt[4][NASP];
    __shared__ int basearr[NASP];
    __shared__ int countsarr[NASP];
    __shared__ int chasp[MAXCHUNK];
    __shared__ int smpall[MAXCHUNK][CH];
    __shared__ int nchunks_s;
    __shared__ __align__(16) float Vs[DROWS][CH];     // 12 KB transposed V tile
    __shared__ __align__(16) float4 red[4][4][32];    // 8 KB [j][wave][col]

    int t = threadIdx.x;
    int lane = t & 63;
    int wave = t >> 6;
    int myaid = aspect_ids[t];

    // --- deterministic bucketing (identical in every block) ---
    unsigned long long mymask = 0ull;
    for (int a = 0; a < NASP; ++a) {
        bool p = (myaid == a);
        unsigned long long m = __ballot(p);
        if (p) mymask = m;
        if (lane == a) wcnt[wave][a] = __popcll(m);
    }
    __syncthreads();
    if (t < NASP) {
        int ctot = wcnt[0][t] + wcnt[1][t] + wcnt[2][t] + wcnt[3][t];
        countsarr[t] = ctot;
        int nc = (ctot + CH - 1) / CH;
        int incl = nc;
        #pragma unroll
        for (int off = 1; off < NASP; off <<= 1) {
            int v = __shfl_up(incl, off, 64);
            if (t >= off) incl += v;
        }
        int base = incl - nc;
        basearr[t] = base;
        for (int j = 0; j < nc; ++j) chasp[base + j] = t;
        if (t == NASP - 1) nchunks_s = incl;
    }
    __syncthreads();
    {
        int pre = 0;
        for (int w = 0; w < wave; ++w) pre += wcnt[w][myaid];
        int r = pre + __popcll(mymask & ((1ull << lane) - 1ull));
        int c = basearr[myaid] + r / CH;
        smpall[c][r % CH] = t;
    }
    __syncthreads();

    int bid = blockIdx.x;
    int chunk0 = bid / (NTILE * DSPLIT);
    int rem  = bid % (NTILE * DSPLIT);
    int tile = rem / DSPLIT;
    int dsp  = rem % DSPLIT;

    int c32 = t & 31;     // float4-col within the 128-col tile
    int dg  = t >> 5;     // row offset 0..7
    int dbase = dsp * DROWS;
    int nchunks = nchunks_s;

    for (int chunk = chunk0; chunk < nchunks; chunk += 32) {
        int aspect = chasp[chunk];
        int cnt = countsarr[aspect] - CH * (chunk - basearr[aspect]);
        if (cnt > CH) cnt = CH;

        __syncthreads();   // Vs/red safe to overwrite
        // stage 192 rows x 16 samples, transposed: Vs[d][s]
        #pragma unroll
        for (int r = 0; r < 3; ++r) {
            int id = t + r * 256;   // 768 = 48 row-quads * 16 samples
            int s = id & (CH - 1);
            int f = id >> 4;
            int smp = (s < cnt) ? smpall[chunk][s] : smpall[chunk][0];
            int d = dbase + f * 4;
            const float* src = (dbase < EMBED)
                ? (vX + (size_t)smp * EMBED + d)
                : (vH + (size_t)smp * HID + (d - EMBED));
            float4 v = *(const float4*)src;
            Vs[f * 4 + 0][s] = v.x;
            Vs[f * 4 + 1][s] = v.y;
            Vs[f * 4 + 2][s] = v.z;
            Vs[f * 4 + 3][s] = v.w;
        }
        __syncthreads();

        const float* wp = W1 + (size_t)aspect * ((size_t)DTOT * HID)
                             + (size_t)(dbase + dg) * HID + tile * 128 + c32 * 4;

        float4 acc[CH];
        #pragma unroll
        for (int s = 0; s < CH; ++s) { acc[s].x = acc[s].y = acc[s].z = acc[s].w = 0.f; }

        #pragma unroll 4
        for (int k = 0; k < DROWS / 8; ++k) {   // 24 iterations
            float4 w = *(const float4*)wp;
            wp += 8 * HID;
            int d = k * 8 + dg;
            float4 va = *(const float4*)&Vs[d][0];
            float4 vb = *(const float4*)&Vs[d][4];
            float4 vc = *(const float4*)&Vs[d][8];
            float4 vd = *(const float4*)&Vs[d][12];
            acc[0].x  += va.x * w.x; acc[0].y  += va.x * w.y; acc[0].z  += va.x * w.z; acc[0].w  += va.x * w.w;
            acc[1].x  += va.y * w.x; acc[1].y  += va.y * w.y; acc[1].z  += va.y * w.z; acc[1].w  += va.y * w.w;
            acc[2].x  += va.z * w.x; acc[2].y  += va.z * w.y; acc[2].z  += va.z * w.z; acc[2].w  += va.z * w.w;
            acc[3].x  += va.w * w.x; acc[3].y  += va.w * w.y; acc[3].z  += va.w * w.z; acc[3].w  += va.w * w.w;
            acc[4].x  += vb.x * w.x; acc[4].y  += vb.x * w.y; acc[4].z  += vb.x * w.z; acc[4].w  += vb.x * w.w;
            acc[5].x  += vb.y * w.x; acc[5].y  += vb.y * w.y; acc[5].z  += vb.y * w.z; acc[5].w  += vb.y * w.w;
            acc[6].x  += vb.z * w.x; acc[6].y  += vb.z * w.y; acc[6].z  += vb.z * w.z; acc[6].w  += vb.z * w.w;
            acc[7].x  += vb.w * w.x; acc[7].y  += vb.w * w.y; acc[7].z  += vb.w * w.z; acc[7].w  += vb.w * w.w;
            acc[8].x  += vc.x * w.x; acc[8].y  += vc.x * w.y; acc[8].z  += vc.x * w.z; acc[8].w  += vc.x * w.w;
            acc[9].x  += vc.y * w.x; acc[9].y  += vc.y * w.y; acc[9].z  += vc.y * w.z; acc[9].w  += vc.y * w.w;
            acc[10].x += vc.z * w.x; acc[10].y += vc.z * w.y; acc[10].z += vc.z * w.z; acc[10].w += vc.z * w.w;
            acc[11].x += vc.w * w.x; acc[11].y += vc.w * w.y; acc[11].z += vc.w * w.z; acc[11].w += vc.w * w.w;
            acc[12].x += vd.x * w.x; acc[12].y += vd.x * w.y; acc[12].z += vd.x * w.z; acc[12].w += vd.x * w.w;
            acc[13].x += vd.y * w.x; acc[13].y += vd.y * w.y; acc[13].z += vd.y * w.z; acc[13].w += vd.y * w.w;
            acc[14].x += vd.z * w.x; acc[14].y += vd.z * w.y; acc[14].z += vd.z * w.z; acc[14].w += vd.z * w.w;
            acc[15].x += vd.w * w.x; acc[15].y += vd.w * w.y; acc[15].z += vd.w * w.z; acc[15].w += vd.w * w.w;
        }

        // fold dg pairs in-wave: lanes 0..31 of wave w hold dg={2w,2w+1} sums
        #pragma unroll
        for (int s = 0; s < CH; ++s) {
            float4 v = acc[s];
            v.x += __shfl_down(v.x, 32, 64); v.y += __shfl_down(v.y, 32, 64);
            v.z += __shfl_down(v.z, 32, 64); v.w += __shfl_down(v.w, 32, 64);
            acc[s] = v;
        }

        // cross-wave reduce, 4 samples per round; write part
        size_t dsp_off = (size_t)dsp * BATCHN * HID;
        #pragma unroll
        for (int rr = 0; rr < 4; ++rr) {
            __syncthreads();
            if (lane < 32) {
                #pragma unroll
                for (int j = 0; j < 4; ++j)
                    red[j][wave][lane] = acc[rr * 4 + j];
            }
            __syncthreads();
            if (t < 128) {            // j = t>>5 (sample-in-round), c = t&31
                int j = t >> 5;
                int c = t & 31;
                int s = rr * 4 + j;
                float4 a0 = red[j][0][c], a1 = red[j][1][c];
                float4 a2 = red[j][2][c], a3 = red[j][3][c];
                float4 sum;
                sum.x = a0.x + a1.x + a2.x + a3.x;
                sum.y = a0.y + a1.y + a2.y + a3.y;
                sum.z = a0.z + a1.z + a2.z + a3.z;
                sum.w = a0.w + a1.w + a2.w + a3.w;
                if (s < cnt) {
                    int smp = smpall[chunk][s];
                    *(float4*)&part[dsp_off + (size_t)smp * HID + tile * 128 + c * 4] = sum;
                }
            }
        }
    }
}

__global__ __launch_bounds__(64) void head_kernel(
    const float* __restrict__ part, const int* __restrict__ aspect_ids,
    const float* __restrict__ b1, const float* __restrict__ W2,
    const float* __restrict__ b2, float* __restrict__ logits)
{
    int s = blockIdx.x;
    int t = threadIdx.x;
    int a = aspect_ids[s];
    const float* w2 = W2 + (size_t)a * HID * 2;
    const float* b1p = b1 + (size_t)a * HID;
    float p0 = 0.f, p1 = 0.f;
    #pragma unroll
    for (int j = 0; j < HID / 64; ++j) {
        int hh = t + j * 64;
        float o = 0.f;
        #pragma unroll
        for (int p = 0; p < DSPLIT; ++p) {
            o += part[(size_t)p * BATCHN * HID + (size_t)s * HID + hh];
        }
        o = fmaxf(o + b1p[hh], 0.f);
        p0 += o * w2[hh * 2 + 0];
        p1 += o * w2[hh * 2 + 1];
    }
    #pragma unroll
    for (int off = 32; off > 0; off >>= 1) {
        p0 += __shfl_down(p0, off, 64);
        p1 += __shfl_down(p1, off, 64);
    }
    if (t == 0) {
        logits[s * 2 + 0] = p0 + b2[a * 2 + 0];
        logits[s * 2 + 1] = p1 + b2[a * 2 + 1];
    }
}

extern "C" void kernel_launch(void* const* d_in, const int* in_sizes, int n_in,
                              void* d_out, int out_size, void* d_ws, size_t ws_size,
                              hipStream_t stream) {
    const float* vX  = (const float*)d_in[0];
    const float* vH  = (const float*)d_in[1];
    const int*   aid = (const int*)d_in[2];
    const float* W1  = (const float*)d_in[3];
    const float* b1  = (const float*)d_in[4];
    const float* W2  = (const float*)d_in[5];
    const float* b2  = (const float*)d_in[6];
    float* logits = (float*)d_out;

    float* part = (float*)d_ws;   // 8*256*768*4 = 6.29 MB

    gemv1_kernel<<<32 * NTILE * DSPLIT, 256, 0, stream>>>(vX, vH, W1, aid, part);
    head_kernel<<<BATCHN, 64, 0, stream>>>(part, aid, b1, W2, b2, logits);
}

// Round 9
// 53.368 us; speedup vs baseline: 4.3117x; 4.3117x over previous
//
#include <hip/hip_runtime.h>
#include <hip/hip_bf16.h>

#define EMBED 768
#define HID 768
#define DTOT 1536
#define NASP 32
#define BATCHN 256
#define CH 16        // samples per chunk
#define MAXCHUNK 48  // sum ceil(n_a/16) <= 48 (chunks >=32 via +32 loop)
#define NTILE 6      // 768 / 128 column tiles
#define DSPLIT 4     // 1536 / 384 row splits
#define DROWS (DTOT / DSPLIT)   // 384 rows per block, staged in ONE shot

// grid = 32*NTILE*DSPLIT = 768 blocks, 3/CU, all co-resident (4/CU limit from
// VGPR ~110 and LDS ~37KB). Single V-stage -> only 2 barriers before epilogue.

__global__ __launch_bounds__(256, 4) void gemv1_kernel(
    const float* __restrict__ vX, const float* __restrict__ vH,
    const float* __restrict__ W1, const int* __restrict__ aspect_ids,
    float* __restrict__ part)
{
    __shared__ int wcnt[4][NASP];
    __shared__ int basearr[NASP];
    __shared__ int countsarr[NASP];
    __shared__ int chasp[MAXCHUNK];
    __shared__ int smpall[MAXCHUNK][CH];
    __shared__ int nchunks_s;
    __shared__ __align__(16) float Vs[DROWS][CH];     // 24 KB transposed V tile
    __shared__ __align__(16) float4 red[4][4][32];    // 8 KB [j][wave][col]

    int t = threadIdx.x;
    int lane = t & 63;
    int wave = t >> 6;
    int myaid = aspect_ids[t];

    // --- deterministic bucketing (identical in every block) ---
    unsigned long long mymask = 0ull;
    for (int a = 0; a < NASP; ++a) {
        bool p = (myaid == a);
        unsigned long long m = __ballot(p);
        if (p) mymask = m;
        if (lane == a) wcnt[wave][a] = __popcll(m);
    }
    __syncthreads();
    if (t < NASP) {
        int ctot = wcnt[0][t] + wcnt[1][t] + wcnt[2][t] + wcnt[3][t];
        countsarr[t] = ctot;
        int nc = (ctot + CH - 1) / CH;
        int incl = nc;
        #pragma unroll
        for (int off = 1; off < NASP; off <<= 1) {
            int v = __shfl_up(incl, off, 64);
            if (t >= off) incl += v;
        }
        int base = incl - nc;
        basearr[t] = base;
        for (int j = 0; j < nc; ++j) chasp[base + j] = t;
        if (t == NASP - 1) nchunks_s = incl;
    }
    __syncthreads();
    {
        int pre = 0;
        for (int w = 0; w < wave; ++w) pre += wcnt[w][myaid];
        int r = pre + __popcll(mymask & ((1ull << lane) - 1ull));
        int c = basearr[myaid] + r / CH;
        smpall[c][r % CH] = t;
    }
    __syncthreads();

    int bid = blockIdx.x;
    int chunk0 = bid / (NTILE * DSPLIT);
    int rem  = bid % (NTILE * DSPLIT);
    int tile = rem / DSPLIT;
    int dsp  = rem % DSPLIT;

    int c32 = t & 31;     // float4-col within the 128-col tile
    int dg  = t >> 5;     // row offset 0..7
    int dbase = dsp * DROWS;
    int nchunks = nchunks_s;

    for (int chunk = chunk0; chunk < nchunks; chunk += 32) {
        int aspect = chasp[chunk];
        int cnt = countsarr[aspect] - CH * (chunk - basearr[aspect]);
        if (cnt > CH) cnt = CH;

        __syncthreads();   // Vs/red safe to overwrite
        // stage 384 rows x 16 samples, transposed: Vs[d][s]; 1536 float4 loads
        #pragma unroll
        for (int r = 0; r < 6; ++r) {
            int id = t + r * 256;   // 1536 = 96 row-quads * 16 samples
            int s = id & (CH - 1);
            int f = id >> 4;        // 0..95
            int smp = (s < cnt) ? smpall[chunk][s] : smpall[chunk][0];
            int d = dbase + f * 4;
            const float* src = (dbase < EMBED)
                ? (vX + (size_t)smp * EMBED + d)
                : (vH + (size_t)smp * HID + (d - EMBED));
            float4 v = *(const float4*)src;
            Vs[f * 4 + 0][s] = v.x;
            Vs[f * 4 + 1][s] = v.y;
            Vs[f * 4 + 2][s] = v.z;
            Vs[f * 4 + 3][s] = v.w;
        }
        __syncthreads();

        const float* wp = W1 + (size_t)aspect * ((size_t)DTOT * HID)
                             + (size_t)(dbase + dg) * HID + tile * 128 + c32 * 4;

        float4 acc[CH];
        #pragma unroll
        for (int s = 0; s < CH; ++s) { acc[s].x = acc[s].y = acc[s].z = acc[s].w = 0.f; }

        #pragma unroll 4
        for (int k = 0; k < DROWS / 8; ++k) {   // 48 iterations
            float4 w = *(const float4*)wp;
            wp += 8 * HID;
            int d = k * 8 + dg;
            float4 va = *(const float4*)&Vs[d][0];
            float4 vb = *(const float4*)&Vs[d][4];
            float4 vc = *(const float4*)&Vs[d][8];
            float4 vd = *(const float4*)&Vs[d][12];
            acc[0].x  += va.x * w.x; acc[0].y  += va.x * w.y; acc[0].z  += va.x * w.z; acc[0].w  += va.x * w.w;
            acc[1].x  += va.y * w.x; acc[1].y  += va.y * w.y; acc[1].z  += va.y * w.z; acc[1].w  += va.y * w.w;
            acc[2].x  += va.z * w.x; acc[2].y  += va.z * w.y; acc[2].z  += va.z * w.z; acc[2].w  += va.z * w.w;
            acc[3].x  += va.w * w.x; acc[3].y  += va.w * w.y; acc[3].z  += va.w * w.z; acc[3].w  += va.w * w.w;
            acc[4].x  += vb.x * w.x; acc[4].y  += vb.x * w.y; acc[4].z  += vb.x * w.z; acc[4].w  += vb.x * w.w;
            acc[5].x  += vb.y * w.x; acc[5].y  += vb.y * w.y; acc[5].z  += vb.y * w.z; acc[5].w  += vb.y * w.w;
            acc[6].x  += vb.z * w.x; acc[6].y  += vb.z * w.y; acc[6].z  += vb.z * w.z; acc[6].w  += vb.z * w.w;
            acc[7].x  += vb.w * w.x; acc[7].y  += vb.w * w.y; acc[7].z  += vb.w * w.z; acc[7].w  += vb.w * w.w;
            acc[8].x  += vc.x * w.x; acc[8].y  += vc.x * w.y; acc[8].z  += vc.x * w.z; acc[8].w  += vc.x * w.w;
            acc[9].x  += vc.y * w.x; acc[9].y  += vc.y * w.y; acc[9].z  += vc.y * w.z; acc[9].w  += vc.y * w.w;
            acc[10].x += vc.z * w.x; acc[10].y += vc.z * w.y; acc[10].z += vc.z * w.z; acc[10].w += vc.z * w.w;
            acc[11].x += vc.w * w.x; acc[11].y += vc.w * w.y; acc[11].z += vc.w * w.z; acc[11].w += vc.w * w.w;
            acc[12].x += vd.x * w.x; acc[12].y += vd.x * w.y; acc[12].z += vd.x * w.z; acc[12].w += vd.x * w.w;
            acc[13].x += vd.y * w.x; acc[13].y += vd.y * w.y; acc[13].z += vd.y * w.z; acc[13].w += vd.y * w.w;
            acc[14].x += vd.z * w.x; acc[14].y += vd.z * w.y; acc[14].z += vd.z * w.z; acc[14].w += vd.z * w.w;
            acc[15].x += vd.w * w.x; acc[15].y += vd.w * w.y; acc[15].z += vd.w * w.z; acc[15].w += vd.w * w.w;
        }

        // fold dg pairs in-wave: lanes 0..31 of wave w hold dg={2w,2w+1} sums
        #pragma unroll
        for (int s = 0; s < CH; ++s) {
            float4 v = acc[s];
            v.x += __shfl_down(v.x, 32, 64); v.y += __shfl_down(v.y, 32, 64);
            v.z += __shfl_down(v.z, 32, 64); v.w += __shfl_down(v.w, 32, 64);
            acc[s] = v;
        }

        // cross-wave reduce, 4 samples per round; write part
        size_t dsp_off = (size_t)dsp * BATCHN * HID;
        #pragma unroll
        for (int rr = 0; rr < 4; ++rr) {
            __syncthreads();
            if (lane < 32) {
                #pragma unroll
                for (int j = 0; j < 4; ++j)
                    red[j][wave][lane] = acc[rr * 4 + j];
            }
            __syncthreads();
            if (t < 128) {            // j = t>>5 (sample-in-round), c = t&31
                int j = t >> 5;
                int c = t & 31;
                int s = rr * 4 + j;
                float4 a0 = red[j][0][c], a1 = red[j][1][c];
                float4 a2 = red[j][2][c], a3 = red[j][3][c];
                float4 sum;
                sum.x = a0.x + a1.x + a2.x + a3.x;
                sum.y = a0.y + a1.y + a2.y + a3.y;
                sum.z = a0.z + a1.z + a2.z + a3.z;
                sum.w = a0.w + a1.w + a2.w + a3.w;
                if (s < cnt) {
                    int smp = smpall[chunk][s];
                    *(float4*)&part[dsp_off + (size_t)smp * HID + tile * 128 + c * 4] = sum;
                }
            }
        }
    }
}

__global__ __launch_bounds__(64) void head_kernel(
    const float* __restrict__ part, const int* __restrict__ aspect_ids,
    const float* __restrict__ b1, const float* __restrict__ W2,
    const float* __restrict__ b2, float* __restrict__ logits)
{
    int s = blockIdx.x;
    int t = threadIdx.x;
    int a = aspect_ids[s];
    const float* w2 = W2 + (size_t)a * HID * 2;
    const float* b1p = b1 + (size_t)a * HID;
    float p0 = 0.f, p1 = 0.f;
    #pragma unroll
    for (int j = 0; j < HID / 64; ++j) {
        int hh = t + j * 64;
        float o = 0.f;
        #pragma unroll
        for (int p = 0; p < DSPLIT; ++p) {
            o += part[(size_t)p * BATCHN * HID + (size_t)s * HID + hh];
        }
        o = fmaxf(o + b1p[hh], 0.f);
        p0 += o * w2[hh * 2 + 0];
        p1 += o * w2[hh * 2 + 1];
    }
    #pragma unroll
    for (int off = 32; off > 0; off >>= 1) {
        p0 += __shfl_down(p0, off, 64);
        p1 += __shfl_down(p1, off, 64);
    }
    if (t == 0) {
        logits[s * 2 + 0] = p0 + b2[a * 2 + 0];
        logits[s * 2 + 1] = p1 + b2[a * 2 + 1];
    }
}

extern "C" void kernel_launch(void* const* d_in, const int* in_sizes, int n_in,
                              void* d_out, int out_size, void* d_ws, size_t ws_size,
                              hipStream_t stream) {
    const float* vX  = (const float*)d_in[0];
    const float* vH  = (const float*)d_in[1];
    const int*   aid = (const int*)d_in[2];
    const float* W1  = (const float*)d_in[3];
    const float* b1  = (const float*)d_in[4];
    const float* W2  = (const float*)d_in[5];
    const float* b2  = (const float*)d_in[6];
    float* logits = (float*)d_out;

    float* part = (float*)d_ws;   // 4*256*768*4 = 3.15 MB

    gemv1_kernel<<<32 * NTILE * DSPLIT, 256, 0, stream>>>(vX, vH, W1, aid, part);
    head_kernel<<<BATCHN, 64, 0, stream>>>(part, aid, b1, W2, b2, logits);
}

// Round 10
// 41.268 us; speedup vs baseline: 5.5759x; 1.2932x over previous
//
#include <hip/hip_runtime.h>
#include <hip/hip_bf16.h>

#define EMBED 768
#define HID 768
#define DTOT 1536
#define NASP 32
#define BATCHN 256
#define CH 16        // samples per chunk
#define MAXCHUNK 48  // grid slots; chunks beyond nchunks exit after prologue
#define NTILE 6      // 768 / 128 column tiles
#define DSPLIT 8     // 1536 / 192 row splits
#define DROWS (DTOT / DSPLIT)   // 192 rows per block

// 512-thr block = (chunk, tile, dsp); sg = t>>8 picks the 8-sample half.
// Each thread: 24 W f4-loads (twin sg re-loads same line -> L1 hit),
// acc[8] = 32 VGPRs -> launch_bounds(512,6) -> 3 blocks/CU, 24 waves/CU.

__global__ __launch_bounds__(512, 6) void gemv1_kernel(
    const float* __restrict__ vX, const float* __restrict__ vH,
    const float* __restrict__ W1, const int* __restrict__ aspect_ids,
    float* __restrict__ part)
{
    __shared__ int wcnt[4][NASP];
    __shared__ int basearr[NASP];
    __shared__ int countsarr[NASP];
    __shared__ int chasp[MAXCHUNK];
    __shared__ int smpall[MAXCHUNK][CH];
    __shared__ int nchunks_s;
    __shared__ __align__(16) float Vs[DROWS][CH];       // 12 KB transposed V
    __shared__ __align__(16) float4 red[2][4][4][32];   // 16 KB [sg][j][wave4][col]

    int t = threadIdx.x;
    int lane = t & 63;
    int wave = t >> 6;

    // --- deterministic bucketing on waves 0-3 (identical in every block) ---
    if (t < BATCHN) {
        int myaid = aspect_ids[t];
        unsigned long long mymask = 0ull;
        for (int a = 0; a < NASP; ++a) {
            bool p = (myaid == a);
            unsigned long long m = __ballot(p);
            if (p) mymask = m;
            if (lane == a) wcnt[wave][a] = __popcll(m);
        }
        __syncthreads();
        if (t < NASP) {
            int ctot = wcnt[0][t] + wcnt[1][t] + wcnt[2][t] + wcnt[3][t];
            countsarr[t] = ctot;
            int nc = (ctot + CH - 1) / CH;
            int incl = nc;
            #pragma unroll
            for (int off = 1; off < NASP; off <<= 1) {
                int v = __shfl_up(incl, off, 64);
                if (t >= off) incl += v;
            }
            int base = incl - nc;
            basearr[t] = base;
            for (int j = 0; j < nc; ++j) chasp[base + j] = t;
            if (t == NASP - 1) nchunks_s = incl;
        }
        __syncthreads();
        {
            int myaid2 = myaid;
            int pre = 0;
            for (int w = 0; w < wave; ++w) pre += wcnt[w][myaid2];
            int r = pre + __popcll(mymask & ((1ull << lane) - 1ull));
            int c = basearr[myaid2] + r / CH;
            smpall[c][r % CH] = t;
        }
    } else {
        __syncthreads();
        __syncthreads();
    }
    __syncthreads();

    int bid = blockIdx.x;
    int chunk = bid / (NTILE * DSPLIT);
    if (chunk >= nchunks_s) return;
    int rem  = bid % (NTILE * DSPLIT);
    int tile = rem / DSPLIT;
    int dsp  = rem % DSPLIT;

    int aspect = chasp[chunk];
    int cnt = countsarr[aspect] - CH * (chunk - basearr[aspect]);
    if (cnt > CH) cnt = CH;

    int c32 = t & 31;          // float4-col within the 128-col tile
    int dg  = (t >> 5) & 7;    // row offset 0..7
    int sg  = t >> 8;          // sample-half 0/1
    int dbase = dsp * DROWS;

    // --- stage 192 rows x 16 samples, transposed: Vs[d][s]; 768 f4 loads ---
    {
        int id = t;                  // 0..511
        int s = id & (CH - 1);
        int f = id >> 4;             // 0..31
        int smp = (s < cnt) ? smpall[chunk][s] : smpall[chunk][0];
        int d = dbase + f * 4;
        const float* src = (dbase < EMBED)
            ? (vX + (size_t)smp * EMBED + d)
            : (vH + (size_t)smp * HID + (d - EMBED));
        float4 v = *(const float4*)src;
        Vs[f * 4 + 0][s] = v.x;
        Vs[f * 4 + 1][s] = v.y;
        Vs[f * 4 + 2][s] = v.z;
        Vs[f * 4 + 3][s] = v.w;
    }
    if (t < 256) {
        int id = t + 512;
        int s = id & (CH - 1);
        int f = id >> 4;             // 32..47
        int smp = (s < cnt) ? smpall[chunk][s] : smpall[chunk][0];
        int d = dbase + f * 4;
        const float* src = (dbase < EMBED)
            ? (vX + (size_t)smp * EMBED + d)
            : (vH + (size_t)smp * HID + (d - EMBED));
        float4 v = *(const float4*)src;
        Vs[f * 4 + 0][s] = v.x;
        Vs[f * 4 + 1][s] = v.y;
        Vs[f * 4 + 2][s] = v.z;
        Vs[f * 4 + 3][s] = v.w;
    }
    __syncthreads();

    const float* wp = W1 + (size_t)aspect * ((size_t)DTOT * HID)
                         + (size_t)(dbase + dg) * HID + tile * 128 + c32 * 4;

    float4 acc[8];
    #pragma unroll
    for (int s = 0; s < 8; ++s) { acc[s].x = acc[s].y = acc[s].z = acc[s].w = 0.f; }

    int vofs = sg * 8;
    #pragma unroll 4
    for (int k = 0; k < DROWS / 8; ++k) {   // 24 iterations
        float4 w = *(const float4*)wp;
        wp += 8 * HID;
        int d = k * 8 + dg;
        float4 va = *(const float4*)&Vs[d][vofs + 0];
        float4 vb = *(const float4*)&Vs[d][vofs + 4];
        acc[0].x += va.x * w.x; acc[0].y += va.x * w.y; acc[0].z += va.x * w.z; acc[0].w += va.x * w.w;
        acc[1].x += va.y * w.x; acc[1].y += va.y * w.y; acc[1].z += va.y * w.z; acc[1].w += va.y * w.w;
        acc[2].x += va.z * w.x; acc[2].y += va.z * w.y; acc[2].z += va.z * w.z; acc[2].w += va.z * w.w;
        acc[3].x += va.w * w.x; acc[3].y += va.w * w.y; acc[3].z += va.w * w.z; acc[3].w += va.w * w.w;
        acc[4].x += vb.x * w.x; acc[4].y += vb.x * w.y; acc[4].z += vb.x * w.z; acc[4].w += vb.x * w.w;
        acc[5].x += vb.y * w.x; acc[5].y += vb.y * w.y; acc[5].z += vb.y * w.z; acc[5].w += vb.y * w.w;
        acc[6].x += vb.z * w.x; acc[6].y += vb.z * w.y; acc[6].z += vb.z * w.z; acc[6].w += vb.z * w.w;
        acc[7].x += vb.w * w.x; acc[7].y += vb.w * w.y; acc[7].z += vb.w * w.z; acc[7].w += vb.w * w.w;
    }

    // --- fold dg pairs in-wave: lanes 0..31 of wave hold dg={2w,2w+1} sums ---
    #pragma unroll
    for (int s = 0; s < 8; ++s) {
        float4 v = acc[s];
        v.x += __shfl_down(v.x, 32, 64); v.y += __shfl_down(v.y, 32, 64);
        v.z += __shfl_down(v.z, 32, 64); v.w += __shfl_down(v.w, 32, 64);
        acc[s] = v;
    }

    // wave w (0..7): lanes 0-31 hold dg-pair (w&3) partials for sg = w>>2.
    // cross-wave reduce: 2 rounds x (4 samples per sg x 2 sg) = 16 samples
    size_t dsp_off = (size_t)dsp * BATCHN * HID;
    #pragma unroll
    for (int rr = 0; rr < 2; ++rr) {
        __syncthreads();
        if (lane < 32) {
            #pragma unroll
            for (int j = 0; j < 4; ++j)
                red[wave >> 2][j][wave & 3][lane] = acc[rr * 4 + j];
        }
        __syncthreads();
        if (t < 256) {   // g = t>>7 (sg), j = (t>>5)&3 (sample-in-round), c = t&31
            int g = t >> 7;
            int j = (t >> 5) & 3;
            int c = t & 31;
            int s = g * 8 + rr * 4 + j;
            float4 a0 = red[g][j][0][c], a1 = red[g][j][1][c];
            float4 a2 = red[g][j][2][c], a3 = red[g][j][3][c];
            float4 sum;
            sum.x = a0.x + a1.x + a2.x + a3.x;
            sum.y = a0.y + a1.y + a2.y + a3.y;
            sum.z = a0.z + a1.z + a2.z + a3.z;
            sum.w = a0.w + a1.w + a2.w + a3.w;
            if (s < cnt) {
                int smp = smpall[chunk][s];
                *(float4*)&part[dsp_off + (size_t)smp * HID + tile * 128 + c * 4] = sum;
            }
        }
    }
}

__global__ __launch_bounds__(64) void head_kernel(
    const float* __restrict__ part, const int* __restrict__ aspect_ids,
    const float* __restrict__ b1, const float* __restrict__ W2,
    const float* __restrict__ b2, float* __restrict__ logits)
{
    int s = blockIdx.x;
    int t = threadIdx.x;
    int a = aspect_ids[s];
    const float* w2 = W2 + (size_t)a * HID * 2;
    const float* b1p = b1 + (size_t)a * HID;
    float p0 = 0.f, p1 = 0.f;
    #pragma unroll
    for (int j = 0; j < HID / 64; ++j) {
        int hh = t + j * 64;
        float o = 0.f;
        #pragma unroll
        for (int p = 0; p < DSPLIT; ++p) {
            o += part[(size_t)p * BATCHN * HID + (size_t)s * HID + hh];
        }
        o = fmaxf(o + b1p[hh], 0.f);
        p0 += o * w2[hh * 2 + 0];
        p1 += o * w2[hh * 2 + 1];
    }
    #pragma unroll
    for (int off = 32; off > 0; off >>= 1) {
        p0 += __shfl_down(p0, off, 64);
        p1 += __shfl_down(p1, off, 64);
    }
    if (t == 0) {
        logits[s * 2 + 0] = p0 + b2[a * 2 + 0];
        logits[s * 2 + 1] = p1 + b2[a * 2 + 1];
    }
}

extern "C" void kernel_launch(void* const* d_in, const int* in_sizes, int n_in,
                              void* d_out, int out_size, void* d_ws, size_t ws_size,
                              hipStream_t stream) {
    const float* vX  = (const float*)d_in[0];
    const float* vH  = (const float*)d_in[1];
    const int*   aid = (const int*)d_in[2];
    const float* W1  = (const float*)d_in[3];
    const float* b1  = (const float*)d_in[4];
    const float* W2  = (const float*)d_in[5];
    const float* b2  = (const float*)d_in[6];
    float* logits = (float*)d_out;

    float* part = (float*)d_ws;   // 8*256*768*4 = 6.29 MB

    gemv1_kernel<<<MAXCHUNK * NTILE * DSPLIT, 512, 0, stream>>>(vX, vH, W1, aid, part);
    head_kernel<<<BATCHN, 64, 0, stream>>>(part, aid, b1, W2, b2, logits);
}